// Round 7
// baseline (262.729 us; speedup 1.0000x reference)
//
#include <hip/hip_runtime.h>
#include <hip/hip_fp16.h>
#include <math.h>

#define NROWS 8192
#define DDIM 384
#define HDIM 256
#define CDIM 6
#define LN_EPS 1e-5f
#define DSTR 138   // Dt row stride in halves (69 dwords, odd -> conflict-free scan)
#define NT256 ((NROWS/256) * (NROWS/256 + 1) / 2)    // 528 = 8*66
#define NG1 (NROWS/256)                              // 32 gemm1 blocks (256x256 tiles)
#define KSTRIDE ((size_t)NROWS * 16)                 // keys: [tile128][row][16]

typedef short bf16x8 __attribute__((ext_vector_type(8)));
typedef float f32x4 __attribute__((ext_vector_type(4)));
typedef unsigned short u16x8 __attribute__((ext_vector_type(8)));
typedef unsigned int u32x4 __attribute__((ext_vector_type(4)));

__device__ __forceinline__ bool dj_better(float d1, int j1, float d2, int j2) {
    return (d1 < d2) || (d1 == d2 && j1 < j2);
}

__device__ __forceinline__ unsigned int umin_(unsigned int a, unsigned int b) { return a < b ? a : b; }
__device__ __forceinline__ unsigned int umax_(unsigned int a, unsigned int b) { return a > b ? a : b; }

// fp32 -> fp16 -> monotonic u16 (unsigned order == float order)
__device__ __forceinline__ unsigned short map16f(float v) {
    union { _Float16 f; unsigned short u; } c;
    c.f = (_Float16)v;
    unsigned short b = c.u;
    return (unsigned short)(b ^ (unsigned short)((((short)b) >> 15) | 0x8000));
}

// inverse of map16f: monotonic u16 -> fp16 bits -> float
__device__ __forceinline__ float unmap16(unsigned int m16b) {
    unsigned short fb = (m16b & 0x8000u) ? (unsigned short)(m16b ^ 0x8000u)
                                         : (unsigned short)(~m16b);
    union { unsigned short u; _Float16 f; } cv; cv.u = fb;
    return (float)cv.f;
}

__device__ __forceinline__ unsigned short rne_bf16(float v) {
    unsigned int u = __float_as_uint(v);
    u += 0x7fffu + ((u >> 16) & 1u);
    return (unsigned short)(u >> 16);
}

// branchless unsorted 8-slot top-8 insert -- used by topk_rescore_agg_kernel
__device__ __forceinline__ void ins8(
    unsigned int& s0, unsigned int& s1, unsigned int& s2, unsigned int& s3,
    unsigned int& s4, unsigned int& s5, unsigned int& s6, unsigned int& s7,
    unsigned int& m, unsigned int key)
{
    if (key < m) {
        s0 = (s0 == m) ? key : s0;
        s1 = (s1 == m) ? key : s1;
        s2 = (s2 == m) ? key : s2;
        s3 = (s3 == m) ? key : s3;
        s4 = (s4 == m) ? key : s4;
        s5 = (s5 == m) ? key : s5;
        s6 = (s6 == m) ? key : s6;
        s7 = (s7 == m) ? key : s7;
        m = umax_(umax_(umax_(s0, s1), umax_(s2, s3)),
                  umax_(umax_(s4, s5), umax_(s6, s7)));
    }
}

__device__ __forceinline__ unsigned int max8_(
    unsigned int s0, unsigned int s1, unsigned int s2, unsigned int s3,
    unsigned int s4, unsigned int s5, unsigned int s6, unsigned int s7)
{
    return umax_(umax_(umax_(s0, s1), umax_(s2, s3)),
                 umax_(umax_(s4, s5), umax_(s6, s7)));
}

// branch-free insert into sorted-descending 8-slot list (s[0] = max).
__device__ __forceinline__ void sins8a(unsigned int (&s)[8], unsigned int key)
{
    unsigned int t = umin_(s[0], key);          // drop max(s[0], key)
    s[0] = umax_(t, s[1]); t = umin_(t, s[1]);
    s[1] = umax_(t, s[2]); t = umin_(t, s[2]);
    s[2] = umax_(t, s[3]); t = umin_(t, s[3]);
    s[3] = umax_(t, s[4]); t = umin_(t, s[4]);
    s[4] = umax_(t, s[5]); t = umin_(t, s[5]);
    s[5] = umax_(t, s[6]); t = umin_(t, s[6]);
    s[6] = umax_(t, s[7]); s[7] = umin_(t, s[7]);
}

// 19-comparator optimal sorting network for 8, descending
#define CE_(a, b) { unsigned int hi_ = umax_(a, b), lo_ = umin_(a, b); a = hi_; b = lo_; }
#define SORT8A_DESC(s) \
    CE_(s[0], s[1]) CE_(s[2], s[3]) CE_(s[4], s[5]) CE_(s[6], s[7]) \
    CE_(s[0], s[2]) CE_(s[1], s[3]) CE_(s[4], s[6]) CE_(s[5], s[7]) \
    CE_(s[1], s[2]) CE_(s[5], s[6]) CE_(s[0], s[4]) CE_(s[3], s[7]) \
    CE_(s[1], s[5]) CE_(s[2], s[6]) \
    CE_(s[1], s[4]) CE_(s[3], s[6]) \
    CE_(s[2], s[4]) CE_(s[3], s[5]) \
    CE_(s[3], s[4])

// seed a sorted top-8 state from one 8-element chunk
__device__ __forceinline__ void scan_seed(
    const unsigned short* rowp, int cb0, unsigned int (&s)[8])
{
    u16x8 c0 = *(const u16x8*)rowp;
    s[0] = ((unsigned int)c0[0] << 13) | (unsigned int)(cb0 + 0);
    s[1] = ((unsigned int)c0[1] << 13) | (unsigned int)(cb0 + 1);
    s[2] = ((unsigned int)c0[2] << 13) | (unsigned int)(cb0 + 2);
    s[3] = ((unsigned int)c0[3] << 13) | (unsigned int)(cb0 + 3);
    s[4] = ((unsigned int)c0[4] << 13) | (unsigned int)(cb0 + 4);
    s[5] = ((unsigned int)c0[5] << 13) | (unsigned int)(cb0 + 5);
    s[6] = ((unsigned int)c0[6] << 13) | (unsigned int)(cb0 + 6);
    s[7] = ((unsigned int)c0[7] << 13) | (unsigned int)(cb0 + 7);
    SORT8A_DESC(s)
}

__device__ __forceinline__ void scan_chunk_i(
    const unsigned short* rowp, int cb0, int i, unsigned int (&s)[8])
{
    u16x8 ch = *(const u16x8*)(rowp + i * 8);
    int cb = cb0 + i * 8;
    #pragma unroll
    for (int e = 0; e < 8; ++e)
        sins8a(s, ((unsigned int)ch[e] << 13) | (unsigned int)(cb + e));
}

// dual-chain scan of one 64-col half (r6, verified)
__device__ __forceinline__ void scan_half_dual(
    const unsigned short* rowp, int cb0, unsigned int (&SA)[8])
{
    unsigned int SB[8];
    scan_seed(rowp, cb0, SA);
    scan_seed(rowp + 8, cb0 + 8, SB);
    #pragma unroll
    for (int i = 2; i < 8; i += 2) {
        scan_chunk_i(rowp, cb0, i, SA);
        scan_chunk_i(rowp, cb0, i + 1, SB);
    }
    #pragma unroll
    for (int e = 0; e < 8; ++e) sins8a(SA, SB[e]);
}

__device__ __forceinline__ void scan_store(
    const unsigned int (&SA)[8], unsigned int* __restrict__ keys, int row, int g64)
{
    size_t kb = (size_t)(g64 >> 1) * KSTRIDE + (size_t)row * 16 + (size_t)(g64 & 1) * 8;
    u32x4 o0 = {SA[0], SA[1], SA[2], SA[3]};
    u32x4 o1 = {SA[4], SA[5], SA[6], SA[7]};
    __builtin_nontemporal_store(o0, (u32x4*)&keys[kb]);
    __builtin_nontemporal_store(o1, (u32x4*)&keys[kb + 4]);
}

// ---------------- fused prep: xb/sq/kk (blocks 0..2047) + weight transposes ----------------
__global__ void __launch_bounds__(256) prep_kernel(
    const float* __restrict__ x, const float* __restrict__ W_tau,
    const float* __restrict__ b_tau, unsigned short* __restrict__ xb,
    float* __restrict__ sq, int* __restrict__ kk,
    const float* __restrict__ Wp, unsigned short* __restrict__ wpT,
    const float* __restrict__ Wr, unsigned short* __restrict__ wrT)
{
    int tid = threadIdx.x;
    if (blockIdx.x < NROWS / 4) {
        int wave = tid >> 6, lane = tid & 63;
        int row = blockIdx.x * 4 + wave;
        const float* xr = x + (size_t)row * DDIM;
        unsigned short* xbr = xb + (size_t)row * DDIM;
        float s = 0.f, tp = 0.f;
        #pragma unroll
        for (int q = 0; q < 6; ++q) {
            float v = xr[lane + 64 * q];
            xbr[lane + 64 * q] = rne_bf16(v);
            s = fmaf(v, v, s);
            tp = fmaf(v, W_tau[lane + 64 * q], tp);
        }
        #pragma unroll
        for (int off = 32; off > 0; off >>= 1) {
            s += __shfl_xor(s, off);
            tp += __shfl_xor(tp, off);
        }
        if (lane == 0) {
            sq[row] = s;
            float u = tp + b_tau[0];
            float tau = 1.f / (1.f + expf(-u));
            float kf = rintf(16.f - 12.f * tau);
            int k = (int)kf;
            k = min(16, max(1, k));
            kk[row] = k;
        }
    } else {
        int i = (blockIdx.x - NROWS / 4) * 256 + tid;
        if (i < DDIM * HDIM) {
            int k = i / HDIM, n = i % HDIM;
            wpT[(size_t)n * DDIM + k] = rne_bf16(Wp[i]);
        } else {
            int j = i - DDIM * HDIM;
            if (j < HDIM * HDIM) {
                int k = j / HDIM, n = j % HDIM;
                wrT[(size_t)n * HDIM + k] = rne_bf16(Wr[j]);
            }
        }
    }
}

// ---------------- 512-thread counted-vmcnt pipelined K-loop, 256x256 tile ----------------
// acc[4][8] += A[rowbase:+256, :K] @ B[nbase:+256, :K]^T. Wave grid 4x2:
// wr=(wave>>1)*64, wc=(wave&1)*128. S: 32768 halves (64 KB): A0=0, A1=16K,
// B0=32K, B1=48K (bytes). Same counted-vmcnt schedule as r5 (verified): 4 loads
// per stage, vmcnt(4) steady-state, explicit lgkmcnt(0)+sched_barrier discipline.
// Callers MUST __syncthreads() before aliasing S.
__device__ __forceinline__ void kloop512(
    const unsigned short* __restrict__ A, const unsigned short* __restrict__ B,
    const int K, const int rowbase, const int nbase,
    unsigned short* S, f32x4 (&acc)[4][8])
{
    const int tid = threadIdx.x;
    const int wave = tid >> 6;
    const int lane = tid & 63;
    const int wr = (wave >> 1) * 64;
    const int wc = (wave & 1) * 128;
    const int m16 = lane & 15;
    const int kq = lane >> 4;
    const int er0 = tid >> 2;          // 0..127
    const int eko = tid & 3;
    const int NK = K >> 5;

    auto stage = [&](int kb, int set) {
        const int k0 = kb * 32;
        char* Ad = (char*)S + set * 16384;
        char* Bd = (char*)S + 32768 + set * 16384;
        __builtin_amdgcn_global_load_lds(
            (const __attribute__((address_space(1))) void*)(A + (size_t)(rowbase + er0) * K + k0 + eko * 8),
            (__attribute__((address_space(3))) void*)(Ad + wave * 1024), 16, 0, 0);
        __builtin_amdgcn_global_load_lds(
            (const __attribute__((address_space(1))) void*)(A + (size_t)(rowbase + 128 + er0) * K + k0 + eko * 8),
            (__attribute__((address_space(3))) void*)(Ad + 8192 + wave * 1024), 16, 0, 0);
        __builtin_amdgcn_global_load_lds(
            (const __attribute__((address_space(1))) void*)(B + (size_t)(nbase + er0) * K + k0 + eko * 8),
            (__attribute__((address_space(3))) void*)(Bd + wave * 1024), 16, 0, 0);
        __builtin_amdgcn_global_load_lds(
            (const __attribute__((address_space(1))) void*)(B + (size_t)(nbase + 128 + er0) * K + k0 + eko * 8),
            (__attribute__((address_space(3))) void*)(Bd + 8192 + wave * 1024), 16, 0, 0);
    };

    stage(0, 0);
    stage(1, 1);
    asm volatile("s_waitcnt vmcnt(4)" ::: "memory");
    __builtin_amdgcn_s_barrier();
    __builtin_amdgcn_sched_barrier(0);

    for (int kb = 0; kb < NK; ++kb) {
        const int cur = kb & 1;
        const unsigned short* Ab = S + cur * 8192;
        const unsigned short* Bb = S + 16384 + cur * 8192;
        bf16x8 af[4], bfr[8];
        #pragma unroll
        for (int s = 0; s < 4; ++s)
            af[s] = *(const bf16x8*)&Ab[(wr + s * 16 + m16) * 32 + kq * 8];
        #pragma unroll
        for (int n = 0; n < 8; ++n)
            bfr[n] = *(const bf16x8*)&Bb[(wc + n * 16 + m16) * 32 + kq * 8];
        #pragma unroll
        for (int si = 0; si < 4; ++si)
            #pragma unroll
            for (int nj = 0; nj < 8; ++nj)
                acc[si][nj] = __builtin_amdgcn_mfma_f32_16x16x32_bf16(
                    af[si], bfr[nj], acc[si][nj], 0, 0, 0);
        asm volatile("s_waitcnt lgkmcnt(0)" ::: "memory");
        __builtin_amdgcn_s_barrier();                        // A: group done with buf[cur]
        __builtin_amdgcn_sched_barrier(0);
        if (kb + 2 < NK) {
            stage(kb + 2, cur);
            asm volatile("s_waitcnt vmcnt(4)" ::: "memory");
            __builtin_amdgcn_s_barrier();                    // B: next tile ready
            __builtin_amdgcn_sched_barrier(0);
        } else if (kb + 1 < NK) {
            asm volatile("s_waitcnt vmcnt(0)" ::: "memory");
            __builtin_amdgcn_s_barrier();
            __builtin_amdgcn_sched_barrier(0);
        }
    }
}

__device__ __forceinline__ void epi512(
    const float* __restrict__ bias, float* __restrict__ out,
    unsigned short* __restrict__ hb, const int rowbase, const int nbase,
    f32x4 (&acc)[4][8])
{
    const int lane = threadIdx.x & 63;
    const int wave = threadIdx.x >> 6;
    const int wr = (wave >> 1) * 64;
    const int wc = (wave & 1) * 128;
    const int m16 = lane & 15;
    const int kq = lane >> 4;
    #pragma unroll
    for (int nj = 0; nj < 8; ++nj) {
        int c = nbase + wc + nj * 16 + m16;
        float bc = bias[c];
        #pragma unroll
        for (int si = 0; si < 4; ++si) {
            int r = rowbase + wr + si * 16 + kq * 4;
            #pragma unroll
            for (int v = 0; v < 4; ++v) {
                float val = fmaxf(acc[si][nj][v] + bc, 0.f);
                out[(size_t)(r + v) * HDIM + c] = val;
                if (hb) hb[(size_t)(r + v) * HDIM + c] = rne_bf16(val);
            }
        }
    }
}

// ---------------- standalone GEMM (residual GEMM), 256x256 tiles ----------------
__global__ void __launch_bounds__(512) mfma_gemm512_kernel(
    const unsigned short* __restrict__ A, const unsigned short* __restrict__ WT,
    const float* __restrict__ bias, float* __restrict__ out,
    unsigned short* __restrict__ hb, int K)
{
    __shared__ __align__(16) unsigned short S[32768];
    f32x4 acc[4][8];
    #pragma unroll
    for (int a = 0; a < 4; ++a)
        #pragma unroll
        for (int b = 0; b < 8; ++b)
            acc[a][b] = (f32x4){0.f, 0.f, 0.f, 0.f};
    kloop512(A, WT, K, blockIdx.x * 256, 0, S, acc);
    epi512(bias, out, hb, blockIdx.x * 256, 0, acc);
}

// ---------------- fused: proj-GEMM blocks (0..31) + 256x256 Gram/top-8 tiles ----------------
// 528 dist tiles (4x fewer than 128-tiles): blocks/CU 8.1 -> 2.1, so per-block
// K-loop/staging latency is paid 4x less often and 4x more MFMA hides it.
// Scan: two 128x138 Dt buffers (col-halves), each the PROVEN conflict-free layout;
// pass over 2 row-stages; waves 0-3 scan DtA, 4-7 scan DtB. acc stays in regs
// across phases. LDS: 64 KB staging (K-loop) aliased under 69 KB Dt pair.
// Raw barriers only inside kloop512; every Dt phase boundary is a real
// __syncthreads() (r4 lesson: bare s_barrier is not a compiler fence).
__global__ void __launch_bounds__(512) dist_gemm_fused_kernel(
    const unsigned short* __restrict__ xb, const float* __restrict__ sq,
    unsigned int* __restrict__ keys,
    const unsigned short* __restrict__ wpT, const float* __restrict__ b_proj,
    float* __restrict__ h, unsigned short* __restrict__ hb)
{
    __shared__ __align__(16) unsigned short SMEM[2 * 128 * DSTR];   // 70656 B >= 64 KB staging

    f32x4 acc[4][8];
    #pragma unroll
    for (int a = 0; a < 4; ++a)
        #pragma unroll
        for (int b = 0; b < 8; ++b)
            acc[a][b] = (f32x4){0.f, 0.f, 0.f, 0.f};

    if (blockIdx.x < NG1) {
        const int rb = blockIdx.x * 256;
        kloop512(xb, wpT, DDIM, rb, 0, SMEM, acc);
        epi512(b_proj, h, hb, rb, 0, acc);
        return;
    }

    int t0 = blockIdx.x - NG1;
    int t = (t0 & 7) * (NT256 / 8) + (t0 >> 3);      // XCD-chunked swizzle (528 = 8*66)
    int bi = (int)((sqrtf(8.f * (float)t + 1.f) - 1.f) * 0.5f);
    while ((bi + 1) * (bi + 2) / 2 <= t) ++bi;
    while (bi * (bi + 1) / 2 > t) --bi;
    int bj = t - bi * (bi + 1) / 2;

    const int tid = threadIdx.x;
    const int wave = tid >> 6;
    const int lane = tid & 63;
    const int rowbase = bi * 256;
    const int colbase = bj * 256;
    const int m16 = lane & 15;
    const int kq = lane >> 4;

    kloop512(xb, xb, DDIM, rowbase, colbase, SMEM, acc);
    __syncthreads();   // real fence: staging dead, Dt buffers may alias

    unsigned short* DtA = SMEM;                 // col-half 0 (or r-half for pass 2)
    unsigned short* DtB = SMEM + 128 * DSTR;    // col-half 1

    const int hb128 = (tid >= 256);             // scan group: 0 -> DtA, 1 -> DtB
    const int t2 = tid & 255;
    const int sr = t2 >> 1;                     // scan row 0..127
    const int seg = t2 & 1;                     // 64-col half within 128
    const unsigned short* rowp = (hb128 ? DtB : DtA) + sr * DSTR + seg * 64;

    const int whalf = wave & 1;                 // wave's col-half
    const int wslab = wave >> 2;                // wave's 128-row slab
    const int rl0 = ((wave >> 1) & 1) * 64;     // wave's 64-row offset within slab
    unsigned short* myDt = whalf ? DtB : DtA;

    // ==== pass 1: rows of bi-block, 2 stages of 128 rows ====
    #pragma unroll
    for (int s = 0; s < 2; ++s) {
        if (wslab == s) {
            float sqc[8];
            #pragma unroll
            for (int nj = 0; nj < 8; ++nj)
                sqc[nj] = sq[colbase + whalf * 128 + nj * 16 + m16];
            #pragma unroll
            for (int si = 0; si < 4; ++si)
                #pragma unroll
                for (int nj = 0; nj < 8; ++nj) {
                    int r = rl0 + si * 16 + kq * 4;
                    int c = nj * 16 + m16;
                    #pragma unroll
                    for (int v = 0; v < 4; ++v)
                        myDt[(r + v) * DSTR + c] = map16f(sqc[nj] - 2.0f * acc[si][nj][v]);
                }
        }
        __syncthreads();
        unsigned int SA[8];
        scan_half_dual(rowp, colbase + hb128 * 128 + seg * 64, SA);
        scan_store(SA, keys, rowbase + s * 128 + sr,
                   (colbase >> 6) + hb128 * 2 + seg);
        __syncthreads();
    }

    // ==== pass 2: rows of bj-block via transposed quadrants (off-diagonal only) ====
    if (bi != bj) {
        #pragma unroll
        for (int u = 0; u < 2; ++u) {
            if (wslab == u) {
                #pragma unroll
                for (int si = 0; si < 4; ++si) {
                    float4 sqr4 = *(const float4*)&sq[rowbase + u * 128 + rl0 + si * 16 + kq * 4];
                    float srw[4] = {sqr4.x, sqr4.y, sqr4.z, sqr4.w};
                    #pragma unroll
                    for (int nj = 0; nj < 8; ++nj) {
                        int cl = nj * 16 + m16;
                        int rl = rl0 + si * 16 + kq * 4;
                        unsigned short h4[4];
                        #pragma unroll
                        for (int v = 0; v < 4; ++v)
                            h4[v] = map16f(srw[v] - 2.0f * acc[si][nj][v]);
                        *(unsigned long long*)&myDt[cl * DSTR + rl] = *(unsigned long long*)h4;
                    }
                }
            }
            __syncthreads();
            unsigned int SA[8];
            scan_half_dual(rowp, rowbase + u * 128 + seg * 64, SA);
            scan_store(SA, keys, colbase + hb128 * 128 + sr,
                       (rowbase >> 6) + u * 2 + seg);
            __syncthreads();
        }
    }
}

// ---------------- fused: merge keys -> sorted top-32, eps-certified selective exact
// rescore -> top-k set, bf16 gather-mean ----------------
__global__ void __launch_bounds__(256) topk_rescore_agg_kernel(
    const unsigned int* __restrict__ keys, const float* __restrict__ x,
    const float* __restrict__ sq, const int* __restrict__ kk,
    const unsigned short* __restrict__ hb, unsigned short* __restrict__ aggb)
{
    const int w = threadIdx.x >> 6;
    const int row = blockIdx.x * 4 + w;
    const int lane = threadIdx.x & 63;
    __shared__ int sidx[4][16];

    // -- phase 1: merge 64x16 per-tile keys -> wave top-32, sorted (seeded) --
    const unsigned int* kpb = keys + (size_t)lane * KSTRIDE + (size_t)row * 16;
    u32x4 a0 = __builtin_nontemporal_load((const u32x4*)kpb);
    u32x4 a1 = __builtin_nontemporal_load((const u32x4*)(kpb + 4));
    unsigned int s0 = a0[0], s1 = a0[1], s2 = a0[2], s3 = a0[3];
    unsigned int s4 = a1[0], s5 = a1[1], s6 = a1[2], s7 = a1[3];
    unsigned int m = max8_(s0, s1, s2, s3, s4, s5, s6, s7);
    #pragma unroll
    for (int q = 2; q < 4; ++q) {
        u32x4 v = __builtin_nontemporal_load((const u32x4*)(kpb + q * 4));
        unsigned int gmin = umin_(umin_(v[0], v[1]), umin_(v[2], v[3]));
        if (gmin < m) {
            ins8(s0, s1, s2, s3, s4, s5, s6, s7, m, v[0]);
            ins8(s0, s1, s2, s3, s4, s5, s6, s7, m, v[1]);
            ins8(s0, s1, s2, s3, s4, s5, s6, s7, m, v[2]);
            ins8(s0, s1, s2, s3, s4, s5, s6, s7, m, v[3]);
        }
    }
    unsigned int lmin = umin_(umin_(umin_(s0, s1), umin_(s2, s3)),
                              umin_(umin_(s4, s5), umin_(s6, s7)));
    unsigned int myout = 0;
    for (int t = 0; t < 32; ++t) {
        unsigned int wv = lmin;
        #pragma unroll
        for (int off = 32; off > 0; off >>= 1)
            wv = umin_(wv, (unsigned int)__shfl_xor((int)wv, off));
        if (lane == t) myout = wv;
        if (lmin == wv) {
            s0 = (s0 == wv) ? 0xFFFFFFFFu : s0;
            s1 = (s1 == wv) ? 0xFFFFFFFFu : s1;
            s2 = (s2 == wv) ? 0xFFFFFFFFu : s2;
            s3 = (s3 == wv) ? 0xFFFFFFFFu : s3;
            s4 = (s4 == wv) ? 0xFFFFFFFFu : s4;
            s5 = (s5 == wv) ? 0xFFFFFFFFu : s5;
            s6 = (s6 == wv) ? 0xFFFFFFFFu : s6;
            s7 = (s7 == wv) ? 0xFFFFFFFFu : s7;
            lmin = umin_(umin_(umin_(s0, s1), umin_(s2, s3)),
                         umin_(umin_(s4, s5), umin_(s6, s7)));
        }
    }
    // lane t < 32 holds the t-th smallest key (screened order)
    int myj = (int)(myout & 8191u);
    float dscr = (lane < 32) ? unmap16(myout >> 13) : INFINITY;

    // -- phase 2: eps-certified selective exact rescore --
    const float EPS2 = 2.5f;                 // 2 * (bf16-Gram 6sigma + fp16 round)
    const int k = kk[row];
    float d_k   = __shfl(dscr, k);           // (k+1)-th smallest screened
    float d_km1 = __shfl(dscr, k - 1);       // k-th smallest screened
    bool cin = false, amb = false;
    if (lane < 32) {
        if (lane < k) { cin = (dscr + EPS2 <= d_k); amb = !cin; }
        else          { amb = (dscr < d_km1 + EPS2); }
    }
    unsigned long long cinmask = __ballot(cin);
    unsigned long long ambmask = __ballot(amb);
    int n_in = __popcll(cinmask);
    int msel = k - n_in;                     // how many ambiguous to select

    float d_ex = 0.f;
    if (msel > 0) {
        float xr[6];
        #pragma unroll
        for (int q = 0; q < 6; ++q) xr[q] = x[(size_t)row * DDIM + lane + 64 * q];
        float sqrow = sq[row];
        unsigned long long mm = ambmask;
        while (mm) {
            int c = (int)(__ffsll(mm) - 1);
            mm &= mm - 1;
            int j = __shfl(myj, c);
            const float* xc = x + (size_t)j * DDIM;
            float p = 0.f;
            #pragma unroll
            for (int q = 0; q < 6; ++q) p = fmaf(xr[q], xc[lane + 64 * q], p);
            #pragma unroll
            for (int off = 32; off > 0; off >>= 1) p += __shfl_xor(p, off);
            float d = sqrow + sq[j] - 2.f * p;
            if (lane == c) d_ex = d;
        }
        // rank ambiguous by exact (d, j); select msel smallest
        int selrank = 0;
        unsigned long long mm2 = ambmask;
        while (mm2) {
            int u = (int)(__ffsll(mm2) - 1);
            mm2 &= mm2 - 1;
            float du = __shfl(d_ex, u);
            int ju = __shfl(myj, u);
            if (u != lane && dj_better(du, ju, d_ex, myj)) ++selrank;
        }
        if (amb && selrank < msel)
            sidx[w][n_in + selrank] = myj;
    }
    if (cin) {
        int pos = __popcll(cinmask & ((1ull << lane) - 1ull));
        sidx[w][pos] = myj;
    }
    __syncthreads();

    // -- phase 3: gather-mean of first k neighbors' bf16 h rows --
    float a0f = 0.f, a1f = 0.f, a2f = 0.f, a3f = 0.f;
    for (int t = 0; t < k; ++t) {
        uint2 v = *(const uint2*)(hb + (size_t)sidx[w][t] * HDIM + lane * 4);
        a0f += __uint_as_float(v.x << 16);
        a1f += __uint_as_float(v.x & 0xFFFF0000u);
        a2f += __uint_as_float(v.y << 16);
        a3f += __uint_as_float(v.y & 0xFFFF0000u);
    }
    float inv = 1.f / (float)k;
    unsigned int b0 = rne_bf16(a0f * inv);
    unsigned int b1 = rne_bf16(a1f * inv);
    unsigned int b2 = rne_bf16(a2f * inv);
    unsigned int b3 = rne_bf16(a3f * inv);
    uint2 o; o.x = b0 | (b1 << 16); o.y = b2 | (b3 << 16);
    *(uint2*)(aggb + (size_t)row * HDIM + lane * 4) = o;
}

// ---------------- LayerNorm(h + r) * g + b, then @ W_fc + b_fc (one row per wave) ----------------
__global__ void __launch_bounds__(256) ln_fc_kernel(
    const float* __restrict__ h, const float* __restrict__ r,
    const float* __restrict__ g, const float* __restrict__ bb,
    const float* __restrict__ W_fc, const float* __restrict__ b_fc,
    float* __restrict__ out)
{
    const int row = blockIdx.x * 4 + (threadIdx.x >> 6);
    const int lane = threadIdx.x & 63;
    const float* hp = h + (size_t)row * HDIM;
    const float* rp = r + (size_t)row * HDIM;

    float z[4];
    #pragma unroll
    for (int q = 0; q < 4; ++q)
        z[q] = hp[lane + 64 * q] + rp[lane + 64 * q];

    float s = z[0] + z[1] + z[2] + z[3];
    float s2 = z[0]*z[0] + z[1]*z[1] + z[2]*z[2] + z[3]*z[3];
    #pragma unroll
    for (int off = 32; off > 0; off >>= 1) {
        s += __shfl_xor(s, off);
        s2 += __shfl_xor(s2, off);
    }
    float mu = s / 256.f;
    float rstd = rsqrtf(s2 / 256.f - mu * mu + LN_EPS);

    float p[6] = {0.f, 0.f, 0.f, 0.f, 0.f, 0.f};
    #pragma unroll
    for (int q = 0; q < 4; ++q) {
        int i = lane + 64 * q;
        float val = (z[q] - mu) * rstd * g[i] + bb[i];
        #pragma unroll
        for (int c = 0; c < 6; ++c)
            p[c] = fmaf(val, W_fc[i * 6 + c], p[c]);
    }
    #pragma unroll
    for (int c = 0; c < 6; ++c)
        #pragma unroll
        for (int off = 32; off > 0; off >>= 1) p[c] += __shfl_xor(p[c], off);

    if (lane < 6) {
        float o = p[0];
        o = (lane == 1) ? p[1] : o;
        o = (lane == 2) ? p[2] : o;
        o = (lane == 3) ? p[3] : o;
        o = (lane == 4) ? p[4] : o;
        o = (lane == 5) ? p[5] : o;
        out[(size_t)row * CDIM + lane] = o + b_fc[lane];
    }
}

extern "C" void kernel_launch(void* const* d_in, const int* in_sizes, int n_in,
                              void* d_out, int out_size, void* d_ws, size_t ws_size,
                              hipStream_t stream) {
    const float* x      = (const float*)d_in[0];
    const float* W_proj = (const float*)d_in[1];
    const float* b_proj = (const float*)d_in[2];
    const float* W_tau  = (const float*)d_in[3];
    const float* b_tau  = (const float*)d_in[4];
    const float* W_res  = (const float*)d_in[5];
    const float* b_res  = (const float*)d_in[6];
    const float* ln_g   = (const float*)d_in[7];
    const float* ln_b   = (const float*)d_in[8];
    const float* W_fc   = (const float*)d_in[9];
    const float* b_fc   = (const float*)d_in[10];
    float* out = (float*)d_out;

    char* ws = (char*)d_ws;
    float* sq   = (float*)ws;                        ws += (size_t)NROWS * 4;
    int*   kk   = (int*)ws;                          ws += (size_t)NROWS * 4;
    float* h    = (float*)ws;                        ws += (size_t)NROWS * HDIM * 4;
    float* r    = (float*)ws;                        ws += (size_t)NROWS * HDIM * 4;
    unsigned short* xb   = (unsigned short*)ws;      ws += (size_t)NROWS * DDIM * 2;
    unsigned short* hbuf = (unsigned short*)ws;      ws += (size_t)NROWS * HDIM * 2;
    unsigned short* aggb = (unsigned short*)ws;      ws += (size_t)NROWS * HDIM * 2;
    unsigned short* wpT  = (unsigned short*)ws;      ws += (size_t)DDIM * HDIM * 2;
    unsigned short* wrT  = (unsigned short*)ws;      ws += (size_t)HDIM * HDIM * 2;
    ws = (char*)(((size_t)ws + 255) & ~(size_t)255);
    unsigned int* keys = (unsigned int*)ws;          ws += (size_t)NROWS * 1024 * 4;   // 32 MB

    const int prepW = (DDIM * HDIM + HDIM * HDIM + 255) / 256;
    prep_kernel<<<NROWS / 4 + prepW, 256, 0, stream>>>(
        x, W_tau, b_tau, xb, sq, kk, W_proj, wpT, W_res, wrT);
    dist_gemm_fused_kernel<<<NG1 + NT256, 512, 0, stream>>>(
        xb, sq, keys, wpT, b_proj, h, hbuf);
    topk_rescore_agg_kernel<<<NROWS / 4, 256, 0, stream>>>(keys, x, sq, kk, hbuf, aggb);
    mfma_gemm512_kernel<<<NROWS / 256, 512, 0, stream>>>(
        aggb, wrT, b_res, r, (unsigned short*)nullptr, HDIM);
    ln_fc_kernel<<<NROWS / 4, 256, 0, stream>>>(h, r, ln_g, ln_b, W_fc, b_fc, out);
}

// Round 8
// 223.161 us; speedup vs baseline: 1.1773x; 1.1773x over previous
//
#include <hip/hip_runtime.h>
#include <hip/hip_fp16.h>
#include <math.h>

#define NROWS 8192
#define DDIM 384
#define HDIM 256
#define CDIM 6
#define LN_EPS 1e-5f
#define DSTR 138   // Dt row stride in halves (69 dwords, odd -> conflict-free scan)
#define NTILES ((NROWS/128) * (NROWS/128 + 1) / 2)   // 2080 = 8*260
#define NGEMM1 ((NROWS/128) * (HDIM/128))            // 128
#define KSTRIDE ((size_t)NROWS * 16)                 // keys: [tile128][row][16]

typedef short bf16x8 __attribute__((ext_vector_type(8)));
typedef float f32x4 __attribute__((ext_vector_type(4)));
typedef unsigned short u16x8 __attribute__((ext_vector_type(8)));
typedef unsigned int u32x4 __attribute__((ext_vector_type(4)));

__device__ __forceinline__ bool dj_better(float d1, int j1, float d2, int j2) {
    return (d1 < d2) || (d1 == d2 && j1 < j2);
}

__device__ __forceinline__ unsigned int umin_(unsigned int a, unsigned int b) { return a < b ? a : b; }
__device__ __forceinline__ unsigned int umax_(unsigned int a, unsigned int b) { return a > b ? a : b; }

// fp32 -> fp16 -> monotonic u16 (unsigned order == float order)
__device__ __forceinline__ unsigned short map16f(float v) {
    union { _Float16 f; unsigned short u; } c;
    c.f = (_Float16)v;
    unsigned short b = c.u;
    return (unsigned short)(b ^ (unsigned short)((((short)b) >> 15) | 0x8000));
}

// inverse of map16f: monotonic u16 -> fp16 bits -> float
__device__ __forceinline__ float unmap16(unsigned int m16b) {
    unsigned short fb = (m16b & 0x8000u) ? (unsigned short)(m16b ^ 0x8000u)
                                         : (unsigned short)(~m16b);
    union { unsigned short u; _Float16 f; } cv; cv.u = fb;
    return (float)cv.f;
}

__device__ __forceinline__ unsigned short rne_bf16(float v) {
    unsigned int u = __float_as_uint(v);
    u += 0x7fffu + ((u >> 16) & 1u);
    return (unsigned short)(u >> 16);
}

// branchless unsorted 8-slot top-8 insert -- used by topk_rescore_agg_kernel
__device__ __forceinline__ void ins8(
    unsigned int& s0, unsigned int& s1, unsigned int& s2, unsigned int& s3,
    unsigned int& s4, unsigned int& s5, unsigned int& s6, unsigned int& s7,
    unsigned int& m, unsigned int key)
{
    if (key < m) {
        s0 = (s0 == m) ? key : s0;
        s1 = (s1 == m) ? key : s1;
        s2 = (s2 == m) ? key : s2;
        s3 = (s3 == m) ? key : s3;
        s4 = (s4 == m) ? key : s4;
        s5 = (s5 == m) ? key : s5;
        s6 = (s6 == m) ? key : s6;
        s7 = (s7 == m) ? key : s7;
        m = umax_(umax_(umax_(s0, s1), umax_(s2, s3)),
                  umax_(umax_(s4, s5), umax_(s6, s7)));
    }
}

__device__ __forceinline__ unsigned int max8_(
    unsigned int s0, unsigned int s1, unsigned int s2, unsigned int s3,
    unsigned int s4, unsigned int s5, unsigned int s6, unsigned int s7)
{
    return umax_(umax_(umax_(s0, s1), umax_(s2, s3)),
                 umax_(umax_(s4, s5), umax_(s6, s7)));
}

// branch-free insert into sorted-descending 8-slot list (s[0] = max).
__device__ __forceinline__ void sins8a(unsigned int (&s)[8], unsigned int key)
{
    unsigned int t = umin_(s[0], key);          // drop max(s[0], key)
    s[0] = umax_(t, s[1]); t = umin_(t, s[1]);
    s[1] = umax_(t, s[2]); t = umin_(t, s[2]);
    s[2] = umax_(t, s[3]); t = umin_(t, s[3]);
    s[3] = umax_(t, s[4]); t = umin_(t, s[4]);
    s[4] = umax_(t, s[5]); t = umin_(t, s[5]);
    s[5] = umax_(t, s[6]); t = umin_(t, s[6]);
    s[6] = umax_(t, s[7]); s[7] = umin_(t, s[7]);
}

// 19-comparator optimal sorting network for 8, descending
#define CE_(a, b) { unsigned int hi_ = umax_(a, b), lo_ = umin_(a, b); a = hi_; b = lo_; }
#define SORT8A_DESC(s) \
    CE_(s[0], s[1]) CE_(s[2], s[3]) CE_(s[4], s[5]) CE_(s[6], s[7]) \
    CE_(s[0], s[2]) CE_(s[1], s[3]) CE_(s[4], s[6]) CE_(s[5], s[7]) \
    CE_(s[1], s[2]) CE_(s[5], s[6]) CE_(s[0], s[4]) CE_(s[3], s[7]) \
    CE_(s[1], s[5]) CE_(s[2], s[6]) \
    CE_(s[1], s[4]) CE_(s[3], s[6]) \
    CE_(s[2], s[4]) CE_(s[3], s[5]) \
    CE_(s[3], s[4])

// seed a sorted top-8 state from one 8-element chunk
__device__ __forceinline__ void scan_seed(
    const unsigned short* rowp, int cb0, unsigned int (&s)[8])
{
    u16x8 c0 = *(const u16x8*)rowp;
    s[0] = ((unsigned int)c0[0] << 13) | (unsigned int)(cb0 + 0);
    s[1] = ((unsigned int)c0[1] << 13) | (unsigned int)(cb0 + 1);
    s[2] = ((unsigned int)c0[2] << 13) | (unsigned int)(cb0 + 2);
    s[3] = ((unsigned int)c0[3] << 13) | (unsigned int)(cb0 + 3);
    s[4] = ((unsigned int)c0[4] << 13) | (unsigned int)(cb0 + 4);
    s[5] = ((unsigned int)c0[5] << 13) | (unsigned int)(cb0 + 5);
    s[6] = ((unsigned int)c0[6] << 13) | (unsigned int)(cb0 + 6);
    s[7] = ((unsigned int)c0[7] << 13) | (unsigned int)(cb0 + 7);
    SORT8A_DESC(s)
}

__device__ __forceinline__ void scan_chunk_i(
    const unsigned short* rowp, int cb0, int i, unsigned int (&s)[8])
{
    u16x8 ch = *(const u16x8*)(rowp + i * 8);
    int cb = cb0 + i * 8;
    #pragma unroll
    for (int e = 0; e < 8; ++e)
        sins8a(s, ((unsigned int)ch[e] << 13) | (unsigned int)(cb + e));
}

// dual-chain scan of one 64-col half (r6, verified)
__device__ __forceinline__ void scan_half_dual(
    const unsigned short* rowp, int cb0, unsigned int (&SA)[8])
{
    unsigned int SB[8];
    scan_seed(rowp, cb0, SA);
    scan_seed(rowp + 8, cb0 + 8, SB);
    #pragma unroll
    for (int i = 2; i < 8; i += 2) {
        scan_chunk_i(rowp, cb0, i, SA);
        scan_chunk_i(rowp, cb0, i + 1, SB);
    }
    #pragma unroll
    for (int e = 0; e < 8; ++e) sins8a(SA, SB[e]);
}

// ---------------- fused prep: xb/sq/kk (blocks 0..2047) + weight transposes ----------------
__global__ void __launch_bounds__(256) prep_kernel(
    const float* __restrict__ x, const float* __restrict__ W_tau,
    const float* __restrict__ b_tau, unsigned short* __restrict__ xb,
    float* __restrict__ sq, int* __restrict__ kk,
    const float* __restrict__ Wp, unsigned short* __restrict__ wpT,
    const float* __restrict__ Wr, unsigned short* __restrict__ wrT)
{
    int tid = threadIdx.x;
    if (blockIdx.x < NROWS / 4) {
        int wave = tid >> 6, lane = tid & 63;
        int row = blockIdx.x * 4 + wave;
        const float* xr = x + (size_t)row * DDIM;
        unsigned short* xbr = xb + (size_t)row * DDIM;
        float s = 0.f, tp = 0.f;
        #pragma unroll
        for (int q = 0; q < 6; ++q) {
            float v = xr[lane + 64 * q];
            xbr[lane + 64 * q] = rne_bf16(v);
            s = fmaf(v, v, s);
            tp = fmaf(v, W_tau[lane + 64 * q], tp);
        }
        #pragma unroll
        for (int off = 32; off > 0; off >>= 1) {
            s += __shfl_xor(s, off);
            tp += __shfl_xor(tp, off);
        }
        if (lane == 0) {
            sq[row] = s;
            float u = tp + b_tau[0];
            float tau = 1.f / (1.f + expf(-u));
            float kf = rintf(16.f - 12.f * tau);
            int k = (int)kf;
            k = min(16, max(1, k));
            kk[row] = k;
        }
    } else {
        int i = (blockIdx.x - NROWS / 4) * 256 + tid;
        if (i < DDIM * HDIM) {
            int k = i / HDIM, n = i % HDIM;
            wpT[(size_t)n * DDIM + k] = rne_bf16(Wp[i]);
        } else {
            int j = i - DDIM * HDIM;
            if (j < HDIM * HDIM) {
                int k = j / HDIM, n = j % HDIM;
                wrT[(size_t)n * HDIM + k] = rne_bf16(Wr[j]);
            }
        }
    }
}

// ---------------- counted-vmcnt pipelined MFMA K-loop (r5/r6, verified correct) ----------------
__device__ __forceinline__ void gemm_kloop(
    const unsigned short* __restrict__ A, const unsigned short* __restrict__ B,
    const int K, const int rowbase, const int nbase,
    unsigned short* S, f32x4 (&acc)[4][4])
{
    const int tid = threadIdx.x;
    const int wave = tid >> 6;
    const int lane = tid & 63;
    const int wr = (wave >> 1) * 64;
    const int wc = (wave & 1) * 64;
    const int m16 = lane & 15;
    const int kq = lane >> 4;
    const int er0 = tid >> 2;
    const int er1 = 64 + (tid >> 2);
    const int eko = tid & 3;
    const int NK = K >> 5;

    auto stage = [&](int kb, int set) {
        const int k0 = kb * 32;
        char* Ad = (char*)S + set * 8192;
        char* Bd = (char*)S + 16384 + set * 8192;
        __builtin_amdgcn_global_load_lds(
            (const __attribute__((address_space(1))) void*)(A + (size_t)(rowbase + er0) * K + k0 + eko * 8),
            (__attribute__((address_space(3))) void*)(Ad + (wave * 64) * 16), 16, 0, 0);
        __builtin_amdgcn_global_load_lds(
            (const __attribute__((address_space(1))) void*)(A + (size_t)(rowbase + er1) * K + k0 + eko * 8),
            (__attribute__((address_space(3))) void*)(Ad + (256 + wave * 64) * 16), 16, 0, 0);
        __builtin_amdgcn_global_load_lds(
            (const __attribute__((address_space(1))) void*)(B + (size_t)(nbase + er0) * K + k0 + eko * 8),
            (__attribute__((address_space(3))) void*)(Bd + (wave * 64) * 16), 16, 0, 0);
        __builtin_amdgcn_global_load_lds(
            (const __attribute__((address_space(1))) void*)(B + (size_t)(nbase + er1) * K + k0 + eko * 8),
            (__attribute__((address_space(3))) void*)(Bd + (256 + wave * 64) * 16), 16, 0, 0);
    };

    stage(0, 0);
    stage(1, 1);
    asm volatile("s_waitcnt vmcnt(4)" ::: "memory");
    __builtin_amdgcn_s_barrier();
    __builtin_amdgcn_sched_barrier(0);

    for (int kb = 0; kb < NK; ++kb) {
        const int cur = kb & 1;
        const unsigned short* Ab = S + cur * 4096;
        const unsigned short* Bb = S + 8192 + cur * 4096;
        bf16x8 af[4], bfr[4];
        #pragma unroll
        for (int s = 0; s < 4; ++s) {
            af[s]  = *(const bf16x8*)&Ab[(wr + s * 16 + m16) * 32 + kq * 8];
            bfr[s] = *(const bf16x8*)&Bb[(wc + s * 16 + m16) * 32 + kq * 8];
        }
        #pragma unroll
        for (int si = 0; si < 4; ++si)
            #pragma unroll
            for (int sj = 0; sj < 4; ++sj)
                acc[si][sj] = __builtin_amdgcn_mfma_f32_16x16x32_bf16(
                    af[si], bfr[sj], acc[si][sj], 0, 0, 0);
        asm volatile("s_waitcnt lgkmcnt(0)" ::: "memory");
        __builtin_amdgcn_s_barrier();
        __builtin_amdgcn_sched_barrier(0);
        if (kb + 2 < NK) {
            stage(kb + 2, cur);
            asm volatile("s_waitcnt vmcnt(4)" ::: "memory");
            __builtin_amdgcn_s_barrier();
            __builtin_amdgcn_sched_barrier(0);
        } else if (kb + 1 < NK) {
            asm volatile("s_waitcnt vmcnt(0)" ::: "memory");
            __builtin_amdgcn_s_barrier();
            __builtin_amdgcn_sched_barrier(0);
        }
    }
}

__device__ __forceinline__ void gemm_epilogue(
    const float* __restrict__ bias, float* __restrict__ out,
    unsigned short* __restrict__ hb, const int rowbase, const int nbase,
    f32x4 (&acc)[4][4])
{
    const int lane = threadIdx.x & 63;
    const int wave = threadIdx.x >> 6;
    const int wr = (wave >> 1) * 64;
    const int wc = (wave & 1) * 64;
    const int m16 = lane & 15;
    const int kq = lane >> 4;
    #pragma unroll
    for (int sj = 0; sj < 4; ++sj) {
        int c = nbase + wc + sj * 16 + m16;
        float bc = bias[c];
        #pragma unroll
        for (int si = 0; si < 4; ++si) {
            int r = rowbase + wr + si * 16 + kq * 4;
            #pragma unroll
            for (int v = 0; v < 4; ++v) {
                float val = fmaxf(acc[si][sj][v] + bc, 0.f);
                out[(size_t)(r + v) * HDIM + c] = val;
                if (hb) hb[(size_t)(r + v) * HDIM + c] = rne_bf16(val);
            }
        }
    }
}

// ---------------- fused: proj-GEMM blocks (0..127) + Gram/top-8 tiles (128..) ----------------
// r6 structure (best family). Plain stores for keys (NOT non-temporal): rescore
// launches immediately after, so keys should stay L2-resident for the consumer
// (r6's nt stores forced rescore's 32 MB read to HBM).
__global__ void __launch_bounds__(256) dist_gemm_fused_kernel(
    const unsigned short* __restrict__ xb, const float* __restrict__ sq,
    unsigned int* __restrict__ keys,
    const unsigned short* __restrict__ wpT, const float* __restrict__ b_proj,
    float* __restrict__ h, unsigned short* __restrict__ hb)
{
    __shared__ __align__(16) unsigned short SMEM[128 * DSTR];   // 34.5 KB

    f32x4 acc[4][4];
    #pragma unroll
    for (int a = 0; a < 4; ++a)
        #pragma unroll
        for (int b = 0; b < 4; ++b)
            acc[a][b] = (f32x4){0.f, 0.f, 0.f, 0.f};

    if (blockIdx.x < NGEMM1) {
        const int rb = (blockIdx.x >> 1) * 128;
        const int nb = (blockIdx.x & 1) * 128;
        gemm_kloop(xb, wpT, DDIM, rb, nb, SMEM, acc);
        gemm_epilogue(b_proj, h, hb, rb, nb, acc);
        return;
    }

    int t0 = blockIdx.x - NGEMM1;
    int t = (t0 & 7) * (NTILES / 8) + (t0 >> 3);      // XCD-chunked swizzle
    int bi = (int)((sqrtf(8.f * (float)t + 1.f) - 1.f) * 0.5f);
    while ((bi + 1) * (bi + 2) / 2 <= t) ++bi;
    while (bi * (bi + 1) / 2 > t) --bi;
    int bj = t - bi * (bi + 1) / 2;

    const int tid = threadIdx.x;
    const int wave = tid >> 6;
    const int lane = tid & 63;
    const int rowbase = bi * 128;
    const int colbase = bj * 128;
    const int wr = (wave >> 1) * 64;
    const int wc = (wave & 1) * 64;
    const int m16 = lane & 15;
    const int kq = lane >> 4;

    gemm_kloop(xb, xb, DDIM, rowbase, colbase, SMEM, acc);
    __syncthreads();   // real fence: staging buffers dead, Dt may alias them
    unsigned short* Dt = SMEM;

    const int sr = tid >> 1;          // scan row in tile (0..127)
    const int seg = tid & 1;          // 64-col half
    const unsigned short* rowp = &Dt[sr * DSTR + seg * 64];

    // ==== pass 1: rows of bi-block ====
    {
        float sqc[4];
        #pragma unroll
        for (int sj = 0; sj < 4; ++sj) sqc[sj] = sq[colbase + wc + sj * 16 + m16];
        #pragma unroll
        for (int si = 0; si < 4; ++si)
            #pragma unroll
            for (int sj = 0; sj < 4; ++sj) {
                int r = wr + si * 16 + kq * 4;
                int c = wc + sj * 16 + m16;
                #pragma unroll
                for (int v = 0; v < 4; ++v)
                    Dt[(r + v) * DSTR + c] = map16f(sqc[sj] - 2.0f * acc[si][sj][v]);
            }
        __syncthreads();

        unsigned int SA[8];
        scan_half_dual(rowp, colbase + seg * 64, SA);
        size_t kb = (size_t)bj * KSTRIDE + (size_t)(rowbase + sr) * 16 + seg * 8;
        uint4 o0; o0.x = SA[0]; o0.y = SA[1]; o0.z = SA[2]; o0.w = SA[3];
        uint4 o1; o1.x = SA[4]; o1.y = SA[5]; o1.z = SA[6]; o1.w = SA[7];
        *(uint4*)&keys[kb] = o0;
        *(uint4*)&keys[kb + 4] = o1;
    }

    // ==== pass 2: rows of bj-block via transposed tile (off-diagonal only) ====
    if (bi != bj) {
        __syncthreads();
        #pragma unroll
        for (int si = 0; si < 4; ++si) {
            float4 sqr4 = *(const float4*)&sq[rowbase + wr + si * 16 + kq * 4];
            float srw[4] = {sqr4.x, sqr4.y, sqr4.z, sqr4.w};
            #pragma unroll
            for (int sj = 0; sj < 4; ++sj) {
                int r = wr + si * 16 + kq * 4;
                int c = wc + sj * 16 + m16;
                unsigned short h4[4];
                #pragma unroll
                for (int v = 0; v < 4; ++v)
                    h4[v] = map16f(srw[v] - 2.0f * acc[si][sj][v]);
                *(unsigned long long*)&Dt[c * DSTR + r] = *(unsigned long long*)h4;
            }
        }
        __syncthreads();

        unsigned int SA[8];
        scan_half_dual(rowp, rowbase + seg * 64, SA);
        size_t kb = (size_t)bi * KSTRIDE + (size_t)(colbase + sr) * 16 + seg * 8;
        uint4 o0; o0.x = SA[0]; o0.y = SA[1]; o0.z = SA[2]; o0.w = SA[3];
        uint4 o1; o1.x = SA[4]; o1.y = SA[5]; o1.z = SA[6]; o1.w = SA[7];
        *(uint4*)&keys[kb] = o0;
        *(uint4*)&keys[kb + 4] = o1;
    }
}

// ---------------- fused: merge keys -> sorted top-32, eps-certified selective exact
// rescore -> top-k set, bf16 gather-mean ----------------
__global__ void __launch_bounds__(256) topk_rescore_agg_kernel(
    const unsigned int* __restrict__ keys, const float* __restrict__ x,
    const float* __restrict__ sq, const int* __restrict__ kk,
    const unsigned short* __restrict__ hb, unsigned short* __restrict__ aggb)
{
    const int w = threadIdx.x >> 6;
    const int row = blockIdx.x * 4 + w;
    const int lane = threadIdx.x & 63;
    __shared__ int sidx[4][16];

    // -- phase 1: merge 64x16 per-tile keys -> wave top-32, sorted (seeded) --
    const unsigned int* kpb = keys + (size_t)lane * KSTRIDE + (size_t)row * 16;
    u32x4 a0 = *(const u32x4*)kpb;
    u32x4 a1 = *(const u32x4*)(kpb + 4);
    unsigned int s0 = a0[0], s1 = a0[1], s2 = a0[2], s3 = a0[3];
    unsigned int s4 = a1[0], s5 = a1[1], s6 = a1[2], s7 = a1[3];
    unsigned int m = max8_(s0, s1, s2, s3, s4, s5, s6, s7);
    #pragma unroll
    for (int q = 2; q < 4; ++q) {
        u32x4 v = *(const u32x4*)(kpb + q * 4);
        unsigned int gmin = umin_(umin_(v[0], v[1]), umin_(v[2], v[3]));
        if (gmin < m) {
            ins8(s0, s1, s2, s3, s4, s5, s6, s7, m, v[0]);
            ins8(s0, s1, s2, s3, s4, s5, s6, s7, m, v[1]);
            ins8(s0, s1, s2, s3, s4, s5, s6, s7, m, v[2]);
            ins8(s0, s1, s2, s3, s4, s5, s6, s7, m, v[3]);
        }
    }
    unsigned int lmin = umin_(umin_(umin_(s0, s1), umin_(s2, s3)),
                              umin_(umin_(s4, s5), umin_(s6, s7)));
    unsigned int myout = 0;
    for (int t = 0; t < 32; ++t) {
        unsigned int wv = lmin;
        #pragma unroll
        for (int off = 32; off > 0; off >>= 1)
            wv = umin_(wv, (unsigned int)__shfl_xor((int)wv, off));
        if (lane == t) myout = wv;
        if (lmin == wv) {
            s0 = (s0 == wv) ? 0xFFFFFFFFu : s0;
            s1 = (s1 == wv) ? 0xFFFFFFFFu : s1;
            s2 = (s2 == wv) ? 0xFFFFFFFFu : s2;
            s3 = (s3 == wv) ? 0xFFFFFFFFu : s3;
            s4 = (s4 == wv) ? 0xFFFFFFFFu : s4;
            s5 = (s5 == wv) ? 0xFFFFFFFFu : s5;
            s6 = (s6 == wv) ? 0xFFFFFFFFu : s6;
            s7 = (s7 == wv) ? 0xFFFFFFFFu : s7;
            lmin = umin_(umin_(umin_(s0, s1), umin_(s2, s3)),
                         umin_(umin_(s4, s5), umin_(s6, s7)));
        }
    }
    // lane t < 32 holds the t-th smallest key (screened order)
    int myj = (int)(myout & 8191u);
    float dscr = (lane < 32) ? unmap16(myout >> 13) : INFINITY;

    // -- phase 2: eps-certified selective exact rescore --
    const float EPS2 = 2.5f;                 // 2 * (bf16-Gram 6sigma + fp16 round)
    const int k = kk[row];
    float d_k   = __shfl(dscr, k);           // (k+1)-th smallest screened
    float d_km1 = __shfl(dscr, k - 1);       // k-th smallest screened
    bool cin = false, amb = false;
    if (lane < 32) {
        if (lane < k) { cin = (dscr + EPS2 <= d_k); amb = !cin; }
        else          { amb = (dscr < d_km1 + EPS2); }
    }
    unsigned long long cinmask = __ballot(cin);
    unsigned long long ambmask = __ballot(amb);
    int n_in = __popcll(cinmask);
    int msel = k - n_in;                     // how many ambiguous to select

    float d_ex = 0.f;
    if (msel > 0) {
        float xr[6];
        #pragma unroll
        for (int q = 0; q < 6; ++q) xr[q] = x[(size_t)row * DDIM + lane + 64 * q];
        float sqrow = sq[row];
        unsigned long long mm = ambmask;
        while (mm) {
            int c = (int)(__ffsll(mm) - 1);
            mm &= mm - 1;
            int j = __shfl(myj, c);
            const float* xc = x + (size_t)j * DDIM;
            float p = 0.f;
            #pragma unroll
            for (int q = 0; q < 6; ++q) p = fmaf(xr[q], xc[lane + 64 * q], p);
            #pragma unroll
            for (int off = 32; off > 0; off >>= 1) p += __shfl_xor(p, off);
            float d = sqrow + sq[j] - 2.f * p;
            if (lane == c) d_ex = d;
        }
        // rank ambiguous by exact (d, j); select msel smallest
        int selrank = 0;
        unsigned long long mm2 = ambmask;
        while (mm2) {
            int u = (int)(__ffsll(mm2) - 1);
            mm2 &= mm2 - 1;
            float du = __shfl(d_ex, u);
            int ju = __shfl(myj, u);
            if (u != lane && dj_better(du, ju, d_ex, myj)) ++selrank;
        }
        if (amb && selrank < msel)
            sidx[w][n_in + selrank] = myj;
    }
    if (cin) {
        int pos = __popcll(cinmask & ((1ull << lane) - 1ull));
        sidx[w][pos] = myj;
    }
    __syncthreads();

    // -- phase 3: gather-mean of first k neighbors' bf16 h rows --
    float a0f = 0.f, a1f = 0.f, a2f = 0.f, a3f = 0.f;
    for (int t = 0; t < k; ++t) {
        uint2 v = *(const uint2*)(hb + (size_t)sidx[w][t] * HDIM + lane * 4);
        a0f += __uint_as_float(v.x << 16);
        a1f += __uint_as_float(v.x & 0xFFFF0000u);
        a2f += __uint_as_float(v.y << 16);
        a3f += __uint_as_float(v.y & 0xFFFF0000u);
    }
    float inv = 1.f / (float)k;
    unsigned int b0 = rne_bf16(a0f * inv);
    unsigned int b1 = rne_bf16(a1f * inv);
    unsigned int b2 = rne_bf16(a2f * inv);
    unsigned int b3 = rne_bf16(a3f * inv);
    uint2 o; o.x = b0 | (b1 << 16); o.y = b2 | (b3 << 16);
    *(uint2*)(aggb + (size_t)row * HDIM + lane * 4) = o;
}

// ---------------- fused residual GEMM + LayerNorm + FC ----------------
// r = relu(aggb @ Wres^T + b_res); z = h + r; out = LN(z)*g+b @ W_fc + b_fc.
// 128 blocks x 64 rows. Each wave owns 16 FULL rows (acc[16]: col = nj*16+m16,
// row = rb + wave*16 + kq*4 + v), so the LN row-reduction is a 4-level shfl_xor
// within each 16-lane group -- no LDS round-trip, no r buffer, no ln_fc kernel.
__global__ void __launch_bounds__(256) res_ln_fc_kernel(
    const unsigned short* __restrict__ aggb, const unsigned short* __restrict__ wrT,
    const float* __restrict__ b_res, const float* __restrict__ h,
    const float* __restrict__ ln_g, const float* __restrict__ ln_b,
    const float* __restrict__ W_fc, const float* __restrict__ b_fc,
    float* __restrict__ out)
{
    __shared__ __align__(16) unsigned short S[20480];   // 40 KB: 2 sets x (A 4K + B 16K)
    const int tid = threadIdx.x;
    const int wave = tid >> 6;
    const int lane = tid & 63;
    const int m16 = lane & 15;
    const int kq = lane >> 4;
    const int rb = blockIdx.x * 64;

    f32x4 acc[16];
    #pragma unroll
    for (int n = 0; n < 16; ++n) acc[n] = (f32x4){0.f, 0.f, 0.f, 0.f};

    auto stage = [&](int kb, int set) {
        const int k0 = kb * 32;
        char* Ad = (char*)S + set * 20480;
        char* Bd = (char*)S + set * 20480 + 4096;
        __builtin_amdgcn_global_load_lds(
            (const __attribute__((address_space(1))) void*)(aggb + (size_t)(rb + (tid >> 2)) * HDIM + k0 + (tid & 3) * 8),
            (__attribute__((address_space(3))) void*)(Ad + wave * 1024), 16, 0, 0);
        #pragma unroll
        for (int n0 = 0; n0 < 256; n0 += 64)
            __builtin_amdgcn_global_load_lds(
                (const __attribute__((address_space(1))) void*)(wrT + (size_t)(n0 + (tid >> 2)) * HDIM + k0 + (tid & 3) * 8),
                (__attribute__((address_space(3))) void*)(Bd + n0 * 64 + wave * 1024), 16, 0, 0);
    };

    // r2-proven dbuf pattern: one __syncthreads per iter (real fence; its
    // vmcnt(0) drain retires prefetch + cross-wave read ordering together).
    stage(0, 0);
    __syncthreads();
    for (int kb = 0; kb < HDIM / 32; ++kb) {
        const int cur = kb & 1;
        if (kb + 1 < HDIM / 32) stage(kb + 1, cur ^ 1);
        const unsigned short* Ab = S + cur * 10240;
        const unsigned short* Bb = S + cur * 10240 + 2048;
        bf16x8 af = *(const bf16x8*)&Ab[(wave * 16 + m16) * 32 + kq * 8];
        #pragma unroll
        for (int nj = 0; nj < 16; ++nj) {
            bf16x8 bf_ = *(const bf16x8*)&Bb[(nj * 16 + m16) * 32 + kq * 8];
            acc[nj] = __builtin_amdgcn_mfma_f32_16x16x32_bf16(af, bf_, acc[nj], 0, 0, 0);
        }
        __syncthreads();
    }

    // per-lane column constants (col = nj*16 + m16, fixed across this lane's rows)
    float gr[16], br[16], bres[16], wf[16][6];
    #pragma unroll
    for (int nj = 0; nj < 16; ++nj) {
        int col = nj * 16 + m16;
        gr[nj] = ln_g[col];
        br[nj] = ln_b[col];
        bres[nj] = b_res[col];
        #pragma unroll
        for (int c = 0; c < 6; ++c) wf[nj][c] = W_fc[col * 6 + c];
    }
    const float bfc = (m16 < 6) ? b_fc[m16] : 0.f;

    #pragma unroll
    for (int v = 0; v < 4; ++v) {
        const int row = rb + wave * 16 + kq * 4 + v;
        const float* hrow = h + (size_t)row * HDIM;
        float z[16];
        float s = 0.f, s2 = 0.f;
        #pragma unroll
        for (int nj = 0; nj < 16; ++nj) {
            float r_ = fmaxf(acc[nj][v] + bres[nj], 0.f);
            float zz = hrow[nj * 16 + m16] + r_;
            z[nj] = zz;
            s += zz;
            s2 = fmaf(zz, zz, s2);
        }
        #pragma unroll
        for (int off = 8; off > 0; off >>= 1) {
            s += __shfl_xor(s, off);
            s2 += __shfl_xor(s2, off);
        }
        float mu = s * (1.f / 256.f);
        float rstd = rsqrtf(s2 * (1.f / 256.f) - mu * mu + LN_EPS);
        float p0 = 0.f, p1 = 0.f, p2 = 0.f, p3 = 0.f, p4 = 0.f, p5 = 0.f;
        #pragma unroll
        for (int nj = 0; nj < 16; ++nj) {
            float zn = (z[nj] - mu) * rstd * gr[nj] + br[nj];
            p0 = fmaf(zn, wf[nj][0], p0);
            p1 = fmaf(zn, wf[nj][1], p1);
            p2 = fmaf(zn, wf[nj][2], p2);
            p3 = fmaf(zn, wf[nj][3], p3);
            p4 = fmaf(zn, wf[nj][4], p4);
            p5 = fmaf(zn, wf[nj][5], p5);
        }
        #pragma unroll
        for (int off = 8; off > 0; off >>= 1) {
            p0 += __shfl_xor(p0, off);
            p1 += __shfl_xor(p1, off);
            p2 += __shfl_xor(p2, off);
            p3 += __shfl_xor(p3, off);
            p4 += __shfl_xor(p4, off);
            p5 += __shfl_xor(p5, off);
        }
        float o = p0;
        o = (m16 == 1) ? p1 : o;
        o = (m16 == 2) ? p2 : o;
        o = (m16 == 3) ? p3 : o;
        o = (m16 == 4) ? p4 : o;
        o = (m16 == 5) ? p5 : o;
        if (m16 < 6) out[(size_t)row * CDIM + m16] = o + bfc;
    }
}

extern "C" void kernel_launch(void* const* d_in, const int* in_sizes, int n_in,
                              void* d_out, int out_size, void* d_ws, size_t ws_size,
                              hipStream_t stream) {
    const float* x      = (const float*)d_in[0];
    const float* W_proj = (const float*)d_in[1];
    const float* b_proj = (const float*)d_in[2];
    const float* W_tau  = (const float*)d_in[3];
    const float* b_tau  = (const float*)d_in[4];
    const float* W_res  = (const float*)d_in[5];
    const float* b_res  = (const float*)d_in[6];
    const float* ln_g   = (const float*)d_in[7];
    const float* ln_b   = (const float*)d_in[8];
    const float* W_fc   = (const float*)d_in[9];
    const float* b_fc   = (const float*)d_in[10];
    float* out = (float*)d_out;

    char* ws = (char*)d_ws;
    float* sq   = (float*)ws;                        ws += (size_t)NROWS * 4;
    int*   kk   = (int*)ws;                          ws += (size_t)NROWS * 4;
    float* h    = (float*)ws;                        ws += (size_t)NROWS * HDIM * 4;
    unsigned short* xb   = (unsigned short*)ws;      ws += (size_t)NROWS * DDIM * 2;
    unsigned short* hbuf = (unsigned short*)ws;      ws += (size_t)NROWS * HDIM * 2;
    unsigned short* aggb = (unsigned short*)ws;      ws += (size_t)NROWS * HDIM * 2;
    unsigned short* wpT  = (unsigned short*)ws;      ws += (size_t)DDIM * HDIM * 2;
    unsigned short* wrT  = (unsigned short*)ws;      ws += (size_t)HDIM * HDIM * 2;
    ws = (char*)(((size_t)ws + 255) & ~(size_t)255);
    unsigned int* keys = (unsigned int*)ws;          ws += (size_t)NROWS * 1024 * 4;   // 32 MB

    const int prepW = (DDIM * HDIM + HDIM * HDIM + 255) / 256;
    prep_kernel<<<NROWS / 4 + prepW, 256, 0, stream>>>(
        x, W_tau, b_tau, xb, sq, kk, W_proj, wpT, W_res, wrT);
    dist_gemm_fused_kernel<<<NGEMM1 + NTILES, 256, 0, stream>>>(
        xb, sq, keys, wpT, b_proj, h, hbuf);
    topk_rescore_agg_kernel<<<NROWS / 4, 256, 0, stream>>>(keys, x, sq, kk, hbuf, aggb);
    res_ln_fc_kernel<<<NROWS / 64, 256, 0, stream>>>(
        aggb, wrT, b_res, h, ln_g, ln_b, W_fc, b_fc, out);
}